// Round 5
// baseline (262.517 us; speedup 1.0000x reference)
//
#include <hip/hip_runtime.h>
#include <hip/hip_bf16.h>
#include <math.h>

#define BB 32
#define SS 4096
#define HH 256

typedef __bf16 bf16x8 __attribute__((ext_vector_type(8)));
typedef float f32x4 __attribute__((ext_vector_type(4)));

#define GLOBAL_AS __attribute__((address_space(1)))
#define LDS_AS    __attribute__((address_space(3)))

__device__ inline bf16x8 cvt8(const float4& x, const float4& y) {
    union { __hip_bfloat162 p[4]; bf16x8 v; } u;
    u.p[0] = __float22bfloat162_rn(make_float2(x.x, x.y));
    u.p[1] = __float22bfloat162_rn(make_float2(x.z, x.w));
    u.p[2] = __float22bfloat162_rn(make_float2(y.x, y.y));
    u.p[3] = __float22bfloat162_rn(make_float2(y.z, y.w));
    return u.v;
}

// tanh(x) = 1 - 2/(e^{2x}+1). Clamp-free: exp2 overflow -> +inf -> rcp=0 -> 1;
// underflow -> 0 -> 1-2 = -1. ~5 VALU ops.
__device__ inline float fast_tanh(float x) {
    float e = __builtin_amdgcn_exp2f(x * 2.8853900817779268f);  // 2*log2(e)
    return 1.f - 2.f * __builtin_amdgcn_rcpf(e + 1.f);
}

// ---------------------------------------------------------------------------
// Prep (unchanged): blocks 0..255 swizzle W2 -> bf16 MFMA-B order;
// blocks 256..287: qq[b][h] = hidden[b]@W1[:,h] + W1_b[h] + W2_b[h];
// block 288: M = sum_h |V_w[h]|  (upper bound on V.tanh; V_b cancels).
// w2sw[((kc*16+nt)*64+lane)*8+j] = W2[kc*32+(lane>>4)*8+j][nt*16+(lane&15)]
// ---------------------------------------------------------------------------
__global__ void prep_kernel(const float* __restrict__ W2_w,
                            ushort* __restrict__ w2sw,
                            const float* __restrict__ hidden,
                            const float* __restrict__ W1_w,
                            const float* __restrict__ W1_b,
                            const float* __restrict__ W2_b,
                            const float* __restrict__ V_w,
                            float* __restrict__ qq,
                            float* __restrict__ Mout) {
    __shared__ float red[HH];
    const int t = threadIdx.x;
    if (blockIdx.x < 256) {
        const int i = blockIdx.x * 256 + t;
        const int j    = i & 7;
        const int lane = (i >> 3) & 63;
        const int nt   = (i >> 9) & 15;
        const int kc   = i >> 13;
        const int k = kc * 32 + ((lane >> 4) & 3) * 8 + j;
        const int n = nt * 16 + (lane & 15);
        __hip_bfloat16 h = __float2bfloat16(W2_w[k * HH + n]);
        w2sw[i] = *(ushort*)&h;
    } else if (blockIdx.x < 256 + BB) {
        const int b = blockIdx.x - 256;
        red[t] = hidden[b * HH + t];
        __syncthreads();
        float acc = 0.f;
#pragma unroll 16
        for (int k = 0; k < HH; ++k)
            acc = fmaf(red[k], W1_w[k * HH + t], acc);
        qq[b * HH + t] = acc + W1_b[t] + W2_b[t];
    } else {
        red[t] = fabsf(V_w[t]);
        __syncthreads();
        for (int off = 128; off > 0; off >>= 1) {
            if (t < off) red[t] += red[t + off];
            __syncthreads();
        }
        if (t == 0) Mout[0] = red[0];
    }
}

// ---------------------------------------------------------------------------
// Fused score + partial-context v5: grid (SS/64, BB), block 256 = 4 waves
// (2m x 2n), 64-row tile (round-0 proven epilogue). KEY CHANGE vs all prior
// rounds: A (enc) is DMA-streamed through LDS via global_load_lds ping-pong
// alongside W2, with the T3/T4 counted-vmcnt 2-phase schedule (raw s_barrier,
// s_waitcnt vmcnt(6) — NEVER a full drain in the loop). Rationale: every
// register-rotate variant held only ~1 KB of enc in flight per CU vs the
// ~9 KB needed to sustain the per-CU HBM share (BW x latency) — all stuck at
// ~2 TB/s. DMA staging is register-free; LDS 53.5 KB -> 3 blocks/CU ->
// ~24 KB A-bytes in flight per CU + 3 independent streams.
// Per kc-chunk per wave: 4 W2 insts (16 KB/blk, L2-hot) + 2 A insts (8 KB/blk,
// HBM) = 6 vmem; wait vmcnt(6) releases chunk kc while kc+1 stays in flight.
// ---------------------------------------------------------------------------
__global__ __launch_bounds__(256, 4)
void score_ctx_kernel(const float* __restrict__ enc,
                      const ushort* __restrict__ w2sw,
                      const float* __restrict__ qq,
                      const float* __restrict__ V_w,
                      const float* __restrict__ Mptr,
                      float* __restrict__ wtilde,
                      float* __restrict__ part) {
    __shared__ __align__(16) ushort w2buf[2][8192];   // 2 x 16 KB
    __shared__ __align__(16) float  abuf[2][2048];    // 2 x 8 KB: [64r][32c]
    __shared__ float sc_lds[64];
    __shared__ float accl[4][HH];

    const int t    = threadIdx.x;
    const int b    = blockIdx.y;
    const int c    = blockIdx.x;
    const int s0   = c * 64;
    const int wave = t >> 6;
    const int lane = t & 63;
    const int mw   = wave & 1;
    const int nw   = wave >> 1;
    const int l15  = lane & 15;
    const int quad = lane >> 4;

    const float* encA = enc + ((size_t)(b * SS + s0)) * HH;
    // A-stage source mapping (lds byte = wave*2048 + i*1024 + lane*16):
    // row = wave*16 + i*8 + (lane>>3), float-col = (lane&7)*4  [linear layout]
    const int arow  = wave * 16 + (lane >> 3);
    const int acolf = (lane & 7) * 4;

#define STAGE(KC, NXT)                                                        \
    do {                                                                      \
        const char* gw_ = (const char*)w2sw + (KC) * 16384 + t * 16;          \
        char* lw_ = (char*)&w2buf[(NXT)][0] + wave * 1024;                    \
        _Pragma("unroll")                                                     \
        for (int i_ = 0; i_ < 4; ++i_)                                        \
            __builtin_amdgcn_global_load_lds(                                 \
                (const GLOBAL_AS void*)(gw_ + i_ * 4096),                     \
                (LDS_AS void*)(lw_ + i_ * 4096), 16, 0, 0);                   \
        _Pragma("unroll")                                                     \
        for (int i_ = 0; i_ < 2; ++i_)                                        \
            __builtin_amdgcn_global_load_lds(                                 \
                (const GLOBAL_AS void*)(encA + (size_t)(arow + i_ * 8) * HH + \
                                        (KC) * 32 + acolf),                   \
                (LDS_AS void*)((char*)&abuf[(NXT)][0] + wave * 2048 +         \
                               i_ * 1024), 16, 0, 0);                         \
    } while (0)

    f32x4 acc[2][8];
#pragma unroll
    for (int mt = 0; mt < 2; ++mt)
#pragma unroll
        for (int nt = 0; nt < 8; ++nt) acc[mt][nt] = (f32x4)0.f;

    STAGE(0, 0);   // prologue: chunk 0 in flight (6 vmem/wave)

#pragma unroll
    for (int kc = 0; kc < 8; ++kc) {
        const int cur = kc & 1;
        if (kc < 7) {
            STAGE(kc + 1, cur ^ 1);                      // +6 in flight
            asm volatile("s_waitcnt vmcnt(6)" ::: "memory");  // kc resident
        } else {
            asm volatile("s_waitcnt vmcnt(0)" ::: "memory");
        }
        __builtin_amdgcn_s_barrier();                    // publish chunk kc

        const int r0 = mw * 32 + l15;
        const float4 ax0 = *(const float4*)&abuf[cur][r0 * 32 + quad * 8];
        const float4 ay0 = *(const float4*)&abuf[cur][r0 * 32 + quad * 8 + 4];
        const float4 ax1 = *(const float4*)&abuf[cur][(r0 + 16) * 32 + quad * 8];
        const float4 ay1 = *(const float4*)&abuf[cur][(r0 + 16) * 32 + quad * 8 + 4];
        const bf16x8 af0 = cvt8(ax0, ay0);
        const bf16x8 af1 = cvt8(ax1, ay1);
#pragma unroll
        for (int nt = 0; nt < 8; ++nt) {
            const bf16x8 bfr =
                *(const bf16x8*)&w2buf[cur][((nw * 8 + nt) * 64 + lane) * 8];
            acc[0][nt] = __builtin_amdgcn_mfma_f32_16x16x32_bf16(
                af0, bfr, acc[0][nt], 0, 0, 0);
            acc[1][nt] = __builtin_amdgcn_mfma_f32_16x16x32_bf16(
                af1, bfr, acc[1][nt], 0, 0, 0);
        }
        // all LDS reads of this chunk consumed before the buffer is recycled
        asm volatile("s_waitcnt lgkmcnt(0)" ::: "memory");
        __builtin_amdgcn_s_barrier();
    }
#undef STAGE

    // Epilogue (round-0 proven): C layout col = l15, local row = quad*4 + r.
    float p[2][4] = {{0.f, 0.f, 0.f, 0.f}, {0.f, 0.f, 0.f, 0.f}};
#pragma unroll
    for (int nt = 0; nt < 8; ++nt) {
        const int n = nw * 128 + nt * 16 + l15;
        const float qn = qq[b * HH + n];
        const float vn = V_w[n];
#pragma unroll
        for (int mt = 0; mt < 2; ++mt)
#pragma unroll
            for (int r = 0; r < 4; ++r)
                p[mt][r] = fmaf(vn, fast_tanh(qn + acc[mt][nt][r]), p[mt][r]);
    }
#pragma unroll
    for (int off = 1; off < 16; off <<= 1)
#pragma unroll
        for (int mt = 0; mt < 2; ++mt)
#pragma unroll
            for (int r = 0; r < 4; ++r)
                p[mt][r] += __shfl_xor(p[mt][r], off);

    if (nw == 0 && l15 == 0) {
#pragma unroll
        for (int mt = 0; mt < 2; ++mt)
            *(float4*)&sc_lds[mw * 32 + mt * 16 + quad * 4] =
                make_float4(p[mt][0], p[mt][1], p[mt][2], p[mt][3]);
    }
    __syncthreads();
    const float Mv = Mptr[0];
    if (nw == 1 && l15 == 0) {
#pragma unroll
        for (int mt = 0; mt < 2; ++mt) {
            const int row = mw * 32 + mt * 16 + quad * 4;
            float4 h = *(const float4*)&sc_lds[row];
            float4 v = make_float4(__expf(h.x + p[mt][0] - Mv),
                                   __expf(h.y + p[mt][1] - Mv),
                                   __expf(h.z + p[mt][2] - Mv),
                                   __expf(h.w + p[mt][3] - Mv));
            *(float4*)&sc_lds[row] = v;
            *(float4*)&wtilde[b * SS + s0 + row] = v;
        }
    }
    __syncthreads();

    // Local context partial over this block's 64 rows (enc slice L1/L2-hot).
    const int tr = t >> 6;
    const int h0 = (t & 63) * 4;
    float4 a = make_float4(0.f, 0.f, 0.f, 0.f);
    const float* ep = enc + ((size_t)(b * SS + s0)) * HH;
#pragma unroll
    for (int jj = 0; jj < 16; ++jj) {
        const int j = jj * 4 + tr;
        const float4 e = *(const float4*)(ep + (size_t)j * HH + h0);
        const float w = sc_lds[j];
        a.x = fmaf(w, e.x, a.x);
        a.y = fmaf(w, e.y, a.y);
        a.z = fmaf(w, e.z, a.z);
        a.w = fmaf(w, e.w, a.w);
    }
    *(float4*)&accl[tr][h0] = a;
    __syncthreads();

    part[((size_t)(b * 64 + c)) * HH + t] =
        accl[0][t] + accl[1][t] + accl[2][t] + accl[3][t];
}

// ---------------------------------------------------------------------------
// Finish: grid (BB), block 256. l = sum_s wtilde; weights = wtilde/l;
// ctx = (sum_c part)/l.  (64 partials per b.)
// ---------------------------------------------------------------------------
__global__ __launch_bounds__(256)
void finish_kernel(const float* __restrict__ wtilde,
                   const float* __restrict__ part,
                   float* __restrict__ weights_out,
                   float* __restrict__ ctx_out) {
    __shared__ float red[256];
    __shared__ float linv_s;
    const int b = blockIdx.x;
    const int t = threadIdx.x;

    const float4* wt4 = (const float4*)(wtilde + (size_t)b * SS);
    float4 vals[4];
    float l = 0.f;
#pragma unroll
    for (int i = 0; i < 4; ++i) {
        vals[i] = wt4[i * 256 + t];
        l += vals[i].x + vals[i].y + vals[i].z + vals[i].w;
    }
    red[t] = l;
    __syncthreads();
    for (int off = 128; off > 0; off >>= 1) {
        if (t < off) red[t] += red[t + off];
        __syncthreads();
    }
    if (t == 0) linv_s = 1.f / red[0];
    __syncthreads();
    const float linv = linv_s;

    float4* wo4 = (float4*)(weights_out + (size_t)b * SS);
#pragma unroll
    for (int i = 0; i < 4; ++i) {
        const float4 v = vals[i];
        wo4[i * 256 + t] =
            make_float4(v.x * linv, v.y * linv, v.z * linv, v.w * linv);
    }

    float a = 0.f;
#pragma unroll 8
    for (int c = 0; c < 64; ++c)
        a += part[((size_t)(b * 64 + c)) * HH + t];
    ctx_out[b * HH + t] = a * linv;
}

// ---------------------------------------------------------------------------
extern "C" void kernel_launch(void* const* d_in, const int* in_sizes, int n_in,
                              void* d_out, int out_size, void* d_ws, size_t ws_size,
                              hipStream_t stream) {
    const float* hidden = (const float*)d_in[0];
    const float* enc    = (const float*)d_in[1];
    const float* W1_w   = (const float*)d_in[2];
    const float* W1_b   = (const float*)d_in[3];
    const float* W2_w   = (const float*)d_in[4];
    const float* W2_b   = (const float*)d_in[5];
    const float* V_w    = (const float*)d_in[6];
    const float* V_b    = (const float*)d_in[7];
    (void)V_b;  // cancels in the shifted softmax

    float* out_weights = (float*)d_out;                 // B*S
    float* out_ctx     = (float*)d_out + BB * SS;       // B*H

    float* ws      = (float*)d_ws;
    float* ws_qq   = ws;                                 // 8192
    float* ws_wt   = ws_qq + BB * HH;                    // 131072
    float* ws_part = ws_wt + BB * SS;                    // 524288
    float* ws_M    = ws_part + BB * 64 * HH;             // 1
    ushort* ws_w2  = (ushort*)(ws_M + 4);                // 65536 bf16

    prep_kernel<<<dim3(256 + BB + 1), dim3(256), 0, stream>>>(
        W2_w, ws_w2, hidden, W1_w, W1_b, W2_b, V_w, ws_qq, ws_M);
    score_ctx_kernel<<<dim3(SS / 64, BB), dim3(256), 0, stream>>>(
        enc, ws_w2, ws_qq, V_w, ws_M, ws_wt, ws_part);
    finish_kernel<<<dim3(BB), dim3(256), 0, stream>>>(
        ws_wt, ws_part, out_weights, out_ctx);
}

// Round 6
// 240.037 us; speedup vs baseline: 1.0937x; 1.0937x over previous
//
#include <hip/hip_runtime.h>
#include <hip/hip_bf16.h>
#include <math.h>

#define BB 32
#define SS 4096
#define HH 256

typedef __bf16 bf16x8 __attribute__((ext_vector_type(8)));
typedef float f32x4 __attribute__((ext_vector_type(4)));

#define GLOBAL_AS __attribute__((address_space(1)))
#define LDS_AS    __attribute__((address_space(3)))

__device__ inline bf16x8 cvt8(const float4& x, const float4& y) {
    union { __hip_bfloat162 p[4]; bf16x8 v; } u;
    u.p[0] = __float22bfloat162_rn(make_float2(x.x, x.y));
    u.p[1] = __float22bfloat162_rn(make_float2(x.z, x.w));
    u.p[2] = __float22bfloat162_rn(make_float2(y.x, y.y));
    u.p[3] = __float22bfloat162_rn(make_float2(y.z, y.w));
    return u.v;
}

// tanh(x) = 1 - 2/(e^{2x}+1). Clamp-free: exp2 overflow -> +inf -> rcp=0 -> 1;
// underflow -> 0 -> 1-2 = -1. ~5 VALU ops.
__device__ inline float fast_tanh(float x) {
    float e = __builtin_amdgcn_exp2f(x * 2.8853900817779268f);  // 2*log2(e)
    return 1.f - 2.f * __builtin_amdgcn_rcpf(e + 1.f);
}

// ---------------------------------------------------------------------------
// Prep (unchanged): blocks 0..255 swizzle W2 -> bf16 MFMA-B order;
// blocks 256..287: qq[b][h] = hidden[b]@W1[:,h] + W1_b[h] + W2_b[h];
// block 288: M = sum_h |V_w[h]|  (upper bound on V.tanh; V_b cancels).
// w2sw[((kc*16+nt)*64+lane)*8+j] = W2[kc*32+(lane>>4)*8+j][nt*16+(lane&15)]
// ---------------------------------------------------------------------------
__global__ void prep_kernel(const float* __restrict__ W2_w,
                            ushort* __restrict__ w2sw,
                            const float* __restrict__ hidden,
                            const float* __restrict__ W1_w,
                            const float* __restrict__ W1_b,
                            const float* __restrict__ W2_b,
                            const float* __restrict__ V_w,
                            float* __restrict__ qq,
                            float* __restrict__ Mout) {
    __shared__ float red[HH];
    const int t = threadIdx.x;
    if (blockIdx.x < 256) {
        const int i = blockIdx.x * 256 + t;
        const int j    = i & 7;
        const int lane = (i >> 3) & 63;
        const int nt   = (i >> 9) & 15;
        const int kc   = i >> 13;
        const int k = kc * 32 + ((lane >> 4) & 3) * 8 + j;
        const int n = nt * 16 + (lane & 15);
        __hip_bfloat16 h = __float2bfloat16(W2_w[k * HH + n]);
        w2sw[i] = *(ushort*)&h;
    } else if (blockIdx.x < 256 + BB) {
        const int b = blockIdx.x - 256;
        red[t] = hidden[b * HH + t];
        __syncthreads();
        float acc = 0.f;
#pragma unroll 16
        for (int k = 0; k < HH; ++k)
            acc = fmaf(red[k], W1_w[k * HH + t], acc);
        qq[b * HH + t] = acc + W1_b[t] + W2_b[t];
    } else {
        red[t] = fabsf(V_w[t]);
        __syncthreads();
        for (int off = 128; off > 0; off >>= 1) {
            if (t < off) red[t] += red[t + off];
            __syncthreads();
        }
        if (t == 0) Mout[0] = red[0];
    }
}

// ---------------------------------------------------------------------------
// Fused score + partial-context v6: grid (SS/64, BB), block 256 = 4 waves
// (2m x 2n), 64-row tile. A (enc) + W2 DMA-streamed through ping-pong LDS
// with counted vmcnt (T3/T4). ROUND-5 FIX: the A-tile LDS layout had a
// 16-way bank conflict (row stride 128 B; quarter-wave lanes all hit one
// 4-bank group -> SQ_LDS_BANK_CONFLICT 2.28e7 = ~50 us serialized LDS).
// Per rule #21 (global_load_lds writes linearly): keep LDS dest linear,
// pre-swizzle the GLOBAL source col by 4*((lane&7)^(lane>>3)), and XOR the
// read col with (row&7)*4 -> lds[row*32 + (c ^ (row&7)*4)], quarter-wave
// spreads over all 32 banks 2-way (free, m136). Also accl aliases abuf[0]
// (dead after K-loop): LDS 53.5 -> 48.2 KB -> 3 blocks/CU.
// ---------------------------------------------------------------------------
__global__ __launch_bounds__(256, 4)
void score_ctx_kernel(const float* __restrict__ enc,
                      const ushort* __restrict__ w2sw,
                      const float* __restrict__ qq,
                      const float* __restrict__ V_w,
                      const float* __restrict__ Mptr,
                      float* __restrict__ wtilde,
                      float* __restrict__ part) {
    // layout: [0,32K) w2buf[2][8192]; [32K,48K) abuf[2][2048]f (accl aliases
    // abuf[0] after the K-loop); [48K, +256B) sc_lds
    __shared__ __align__(16) char smem[49408];
    float* sc_lds = (float*)(smem + 49152);
    float* accl   = (float*)(smem + 32768);    // alias abuf[0], [4][256]

    const int t    = threadIdx.x;
    const int b    = blockIdx.y;
    const int c    = blockIdx.x;
    const int s0   = c * 64;
    const int wave = t >> 6;
    const int lane = t & 63;
    const int mw   = wave & 1;
    const int nw   = wave >> 1;
    const int l15  = lane & 15;
    const int quad = lane >> 4;

    const float* encA = enc + ((size_t)(b * SS + s0)) * HH;
    // A-stage: lds float idx = wave*512 + i*256 + lane*4 (linear DMA dest)
    //   -> row = wave*16 + i*8 + (lane>>3), stored col-group = (lane&7)*4
    //   -> fetch global col 4*((lane&7) ^ (lane>>3)) so that
    //      lds[row*32 + (c ^ (row&7)*4)] = enc[row][kc*32 + c]
    const int arow = wave * 16 + (lane >> 3);
    const int aswz = 4 * ((lane & 7) ^ (lane >> 3));

#define STAGE(KC, NXT)                                                        \
    do {                                                                      \
        const char* gw_ = (const char*)w2sw + (KC) * 16384 + t * 16;          \
        char* lw_ = smem + (NXT) * 16384 + wave * 1024;                       \
        _Pragma("unroll")                                                     \
        for (int i_ = 0; i_ < 4; ++i_)                                        \
            __builtin_amdgcn_global_load_lds(                                 \
                (const GLOBAL_AS void*)(gw_ + i_ * 4096),                     \
                (LDS_AS void*)(lw_ + i_ * 4096), 16, 0, 0);                   \
        _Pragma("unroll")                                                     \
        for (int i_ = 0; i_ < 2; ++i_)                                        \
            __builtin_amdgcn_global_load_lds(                                 \
                (const GLOBAL_AS void*)(encA + (size_t)(arow + i_ * 8) * HH + \
                                        (KC) * 32 + aswz),                    \
                (LDS_AS void*)(smem + 32768 + (NXT) * 8192 + wave * 2048 +    \
                               i_ * 1024), 16, 0, 0);                         \
    } while (0)

    f32x4 acc[2][8];
#pragma unroll
    for (int mt = 0; mt < 2; ++mt)
#pragma unroll
        for (int nt = 0; nt < 8; ++nt) acc[mt][nt] = (f32x4)0.f;

    STAGE(0, 0);   // prologue: chunk 0 in flight (6 vmem/wave)

#pragma unroll
    for (int kc = 0; kc < 8; ++kc) {
        const int cur = kc & 1;
        if (kc < 7) {
            STAGE(kc + 1, cur ^ 1);                      // +6 in flight
            asm volatile("s_waitcnt vmcnt(6)" ::: "memory");  // kc resident
        } else {
            asm volatile("s_waitcnt vmcnt(0)" ::: "memory");
        }
        __builtin_amdgcn_s_barrier();                    // publish chunk kc

        const ushort* wbuf = (const ushort*)(smem + cur * 16384);
        const float*  abuf = (const float*)(smem + 32768 + cur * 8192);
        const int r0 = mw * 32 + l15;
        const int sx = (l15 & 7) * 4;                    // read-side swizzle
        const float4 ax0 = *(const float4*)&abuf[r0 * 32 + ((quad * 8) ^ sx)];
        const float4 ay0 = *(const float4*)&abuf[r0 * 32 + ((quad * 8 + 4) ^ sx)];
        const float4 ax1 = *(const float4*)&abuf[(r0 + 16) * 32 + ((quad * 8) ^ sx)];
        const float4 ay1 = *(const float4*)&abuf[(r0 + 16) * 32 + ((quad * 8 + 4) ^ sx)];
        const bf16x8 af0 = cvt8(ax0, ay0);
        const bf16x8 af1 = cvt8(ax1, ay1);
#pragma unroll
        for (int nt = 0; nt < 8; ++nt) {
            const bf16x8 bfr =
                *(const bf16x8*)&wbuf[((nw * 8 + nt) * 64 + lane) * 8];
            acc[0][nt] = __builtin_amdgcn_mfma_f32_16x16x32_bf16(
                af0, bfr, acc[0][nt], 0, 0, 0);
            acc[1][nt] = __builtin_amdgcn_mfma_f32_16x16x32_bf16(
                af1, bfr, acc[1][nt], 0, 0, 0);
        }
        // all LDS reads of this chunk consumed before the buffer is recycled
        asm volatile("s_waitcnt lgkmcnt(0)" ::: "memory");
        __builtin_amdgcn_s_barrier();
    }
#undef STAGE

    // Epilogue: C layout col = l15, local row = quad*4 + r.
    float p[2][4] = {{0.f, 0.f, 0.f, 0.f}, {0.f, 0.f, 0.f, 0.f}};
#pragma unroll
    for (int nt = 0; nt < 8; ++nt) {
        const int n = nw * 128 + nt * 16 + l15;
        const float qn = qq[b * HH + n];
        const float vn = V_w[n];
#pragma unroll
        for (int mt = 0; mt < 2; ++mt)
#pragma unroll
            for (int r = 0; r < 4; ++r)
                p[mt][r] = fmaf(vn, fast_tanh(qn + acc[mt][nt][r]), p[mt][r]);
    }
#pragma unroll
    for (int off = 1; off < 16; off <<= 1)
#pragma unroll
        for (int mt = 0; mt < 2; ++mt)
#pragma unroll
            for (int r = 0; r < 4; ++r)
                p[mt][r] += __shfl_xor(p[mt][r], off);

    if (nw == 0 && l15 == 0) {
#pragma unroll
        for (int mt = 0; mt < 2; ++mt)
            *(float4*)&sc_lds[mw * 32 + mt * 16 + quad * 4] =
                make_float4(p[mt][0], p[mt][1], p[mt][2], p[mt][3]);
    }
    __syncthreads();
    const float Mv = Mptr[0];
    if (nw == 1 && l15 == 0) {
#pragma unroll
        for (int mt = 0; mt < 2; ++mt) {
            const int row = mw * 32 + mt * 16 + quad * 4;
            float4 h = *(const float4*)&sc_lds[row];
            float4 v = make_float4(__expf(h.x + p[mt][0] - Mv),
                                   __expf(h.y + p[mt][1] - Mv),
                                   __expf(h.z + p[mt][2] - Mv),
                                   __expf(h.w + p[mt][3] - Mv));
            *(float4*)&sc_lds[row] = v;
            *(float4*)&wtilde[b * SS + s0 + row] = v;
        }
    }
    __syncthreads();

    // Local context partial over this block's 64 rows (enc slice L1/L2-hot).
    const int tr = t >> 6;
    const int h0 = (t & 63) * 4;
    float4 a = make_float4(0.f, 0.f, 0.f, 0.f);
    const float* ep = enc + ((size_t)(b * SS + s0)) * HH;
#pragma unroll
    for (int jj = 0; jj < 16; ++jj) {
        const int j = jj * 4 + tr;
        const float4 e = *(const float4*)(ep + (size_t)j * HH + h0);
        const float w = sc_lds[j];
        a.x = fmaf(w, e.x, a.x);
        a.y = fmaf(w, e.y, a.y);
        a.z = fmaf(w, e.z, a.z);
        a.w = fmaf(w, e.w, a.w);
    }
    *(float4*)&accl[tr * HH + h0] = a;
    __syncthreads();

    part[((size_t)(b * 64 + c)) * HH + t] =
        accl[0 * HH + t] + accl[1 * HH + t] + accl[2 * HH + t] +
        accl[3 * HH + t];
}

// ---------------------------------------------------------------------------
// Finish: grid (BB), block 256. l = sum_s wtilde; weights = wtilde/l;
// ctx = (sum_c part)/l.  (64 partials per b.)
// ---------------------------------------------------------------------------
__global__ __launch_bounds__(256)
void finish_kernel(const float* __restrict__ wtilde,
                   const float* __restrict__ part,
                   float* __restrict__ weights_out,
                   float* __restrict__ ctx_out) {
    __shared__ float red[256];
    __shared__ float linv_s;
    const int b = blockIdx.x;
    const int t = threadIdx.x;

    const float4* wt4 = (const float4*)(wtilde + (size_t)b * SS);
    float4 vals[4];
    float l = 0.f;
#pragma unroll
    for (int i = 0; i < 4; ++i) {
        vals[i] = wt4[i * 256 + t];
        l += vals[i].x + vals[i].y + vals[i].z + vals[i].w;
    }
    red[t] = l;
    __syncthreads();
    for (int off = 128; off > 0; off >>= 1) {
        if (t < off) red[t] += red[t + off];
        __syncthreads();
    }
    if (t == 0) linv_s = 1.f / red[0];
    __syncthreads();
    const float linv = linv_s;

    float4* wo4 = (float4*)(weights_out + (size_t)b * SS);
#pragma unroll
    for (int i = 0; i < 4; ++i) {
        const float4 v = vals[i];
        wo4[i * 256 + t] =
            make_float4(v.x * linv, v.y * linv, v.z * linv, v.w * linv);
    }

    float a = 0.f;
#pragma unroll 8
    for (int c = 0; c < 64; ++c)
        a += part[((size_t)(b * 64 + c)) * HH + t];
    ctx_out[b * HH + t] = a * linv;
}

// ---------------------------------------------------------------------------
extern "C" void kernel_launch(void* const* d_in, const int* in_sizes, int n_in,
                              void* d_out, int out_size, void* d_ws, size_t ws_size,
                              hipStream_t stream) {
    const float* hidden = (const float*)d_in[0];
    const float* enc    = (const float*)d_in[1];
    const float* W1_w   = (const float*)d_in[2];
    const float* W1_b   = (const float*)d_in[3];
    const float* W2_w   = (const float*)d_in[4];
    const float* W2_b   = (const float*)d_in[5];
    const float* V_w    = (const float*)d_in[6];
    const float* V_b    = (const float*)d_in[7];
    (void)V_b;  // cancels in the shifted softmax

    float* out_weights = (float*)d_out;                 // B*S
    float* out_ctx     = (float*)d_out + BB * SS;       // B*H

    float* ws      = (float*)d_ws;
    float* ws_qq   = ws;                                 // 8192
    float* ws_wt   = ws_qq + BB * HH;                    // 131072
    float* ws_part = ws_wt + BB * SS;                    // 524288
    float* ws_M    = ws_part + BB * 64 * HH;             // 1
    ushort* ws_w2  = (ushort*)(ws_M + 4);                // 65536 bf16

    prep_kernel<<<dim3(256 + BB + 1), dim3(256), 0, stream>>>(
        W2_w, ws_w2, hidden, W1_w, W1_b, W2_b, V_w, ws_qq, ws_M);
    score_ctx_kernel<<<dim3(SS / 64, BB), dim3(256), 0, stream>>>(
        enc, ws_w2, ws_qq, V_w, ws_M, ws_wt, ws_part);
    finish_kernel<<<dim3(BB), dim3(256), 0, stream>>>(
        ws_wt, ws_part, out_weights, out_ctx);
}